// Round 1
// baseline (937.238 us; speedup 1.0000x reference)
//
#include <hip/hip_runtime.h>
#include <hip/hip_bf16.h>

#define TT 4096
#define BB 256
#define DD 3
#define UU 8

// ---------- fast activations ----------
#if defined(__has_builtin)
#if __has_builtin(__builtin_amdgcn_exp2f) && __has_builtin(__builtin_amdgcn_rcpf)
#define FAST_EXP2(x) __builtin_amdgcn_exp2f(x)
#define FAST_RCP(x)  __builtin_amdgcn_rcpf(x)
#endif
#endif
#ifndef FAST_EXP2
#define FAST_EXP2(x) exp2f(x)
#define FAST_RCP(x)  (1.0f / (x))
#endif

__device__ __forceinline__ float fsig(float x) {
    // sigmoid(x) = 1/(1+2^(-x*log2e))
    float e = FAST_EXP2(-1.4426950408889634f * x);
    return FAST_RCP(1.0f + e);
}
__device__ __forceinline__ float ftanh(float x) {
    // tanh(x) = 1 - 2/(1+2^(2x*log2e)) ; saturates correctly at +/-inf
    float e = FAST_EXP2(2.8853900817779268f * x);
    return 1.0f - 2.0f * FAST_RCP(1.0f + e);
}

// ---------- block-wide exclusive scan over 256 threads ----------
__device__ __forceinline__ float block_excl_scan(float v, int tid, float* red) {
    float x = v;
    int lid = tid & 63;
    #pragma unroll
    for (int d = 1; d < 64; d <<= 1) {
        float y = __shfl_up(x, d, 64);
        if (lid >= d) x += y;
    }
    int wave = tid >> 6;
    __syncthreads();                 // protect red[] from previous call's readers
    if (lid == 63) red[wave] = x;    // wave-inclusive total
    __syncthreads();
    float off = 0.0f;
    for (int w = 0; w < wave; ++w) off += red[w];
    return off + (x - v);            // exclusive prefix for this thread's chunk
}

// ---------- Kernel A: signature + forget gate + input projection precompute ----------
// ws layout: [t][b][u] float4 = {gi_pre, gc_pre, go_pre, f_sigmoided}
__global__ __launch_bounds__(256) void sig_pre_kernel(
    const float* __restrict__ x,     // (B,T,3)
    const float* __restrict__ Wi,    // (3,24)
    const float* __restrict__ Wf,    // (21,8)
    const float* __restrict__ bias,  // (32)
    float* __restrict__ ws)
{
    __shared__ float sWf[21 * 8];
    __shared__ float sWi[3 * 24];
    __shared__ float sB[32];
    __shared__ float red[4];

    const int tid = threadIdx.x;
    const int b = blockIdx.x;
    if (tid < 168) sWf[tid] = Wf[tid];
    if (tid < 72)  sWi[tid] = Wi[tid];
    if (tid < 32)  sB[tid]  = bias[tid];
    __syncthreads();

    const float dtc = 1.0f / 4095.0f;
    const int t0 = tid * 16;
    const float* xb = x + (size_t)b * TT * DD;

    // ---- pass 1: local chunk sums of L1 (4) and L2-with-local-L1prev (16) ----
    float l1[4] = {0.f, 0.f, 0.f, 0.f};
    float l2[16];
    #pragma unroll
    for (int i = 0; i < 16; ++i) l2[i] = 0.f;
    {
        int s = (tid == 0) ? 1 : t0;
        float xp0 = xb[(s - 1) * 3 + 0];
        float xp1 = xb[(s - 1) * 3 + 1];
        float xp2 = xb[(s - 1) * 3 + 2];
        for (; s < t0 + 16; ++s) {
            float c0 = xb[s * 3 + 0], c1 = xb[s * 3 + 1], c2 = xb[s * 3 + 2];
            float dxv[4] = {dtc, c0 - xp0, c1 - xp1, c2 - xp2};
            #pragma unroll
            for (int r = 0; r < 4; ++r) {
                float tr = l1[r] + 0.5f * dxv[r];
                #pragma unroll
                for (int cc = 0; cc < 4; ++cc)
                    l2[r * 4 + cc] = fmaf(tr, dxv[cc], l2[r * 4 + cc]);
            }
            #pragma unroll
            for (int r = 0; r < 4; ++r) l1[r] += dxv[r];
            xp0 = c0; xp1 = c1; xp2 = c2;
        }
    }

    // ---- scans: O1 = excl scan of S1 ; O2 = excl scan of (S2 + O1 (x) S1) ----
    float S1[4], O1[4];
    #pragma unroll
    for (int r = 0; r < 4; ++r) { S1[r] = l1[r]; }
    for (int r = 0; r < 4; ++r) O1[r] = block_excl_scan(S1[r], tid, red);
    float O2[16];
    for (int rc = 0; rc < 16; ++rc) {
        float c2v = l2[rc] + O1[rc >> 2] * S1[rc & 3];
        O2[rc] = block_excl_scan(c2v, tid, red);
    }

    // ---- pass 2: walk chunk, emit sig-normalized forget gate + pre-gates ----
    #pragma unroll
    for (int r = 0; r < 4; ++r) l1[r] = O1[r];
    #pragma unroll
    for (int i = 0; i < 16; ++i) l2[i] = O2[i];

    float xp0, xp1, xp2;
    {
        int tp = (tid == 0) ? 0 : (t0 - 1);
        xp0 = xb[tp * 3 + 0]; xp1 = xb[tp * 3 + 1]; xp2 = xb[tp * 3 + 2];
    }
    for (int i2 = 0; i2 < 16; ++i2) {
        const int t = t0 + i2;
        float c0 = xb[t * 3 + 0], c1 = xb[t * 3 + 1], c2 = xb[t * 3 + 2];
        if (t > 0) {
            float dxv[4] = {dtc, c0 - xp0, c1 - xp1, c2 - xp2};
            #pragma unroll
            for (int r = 0; r < 4; ++r) {
                float tr = l1[r] + 0.5f * dxv[r];
                #pragma unroll
                for (int cc = 0; cc < 4; ++cc)
                    l2[r * 4 + cc] = fmaf(tr, dxv[cc], l2[r * 4 + cc]);
            }
            #pragma unroll
            for (int r = 0; r < 4; ++r) l1[r] += dxv[r];
        }
        xp0 = c0; xp1 = c1; xp2 = c2;
        const float scale = (t == 0) ? 1.0f : (4095.0f / (float)t);
        float sg[21];
        sg[0] = scale;
        #pragma unroll
        for (int r = 0; r < 4; ++r) sg[1 + r] = l1[r] * scale;
        #pragma unroll
        for (int rc = 0; rc < 16; ++rc) sg[5 + rc] = l2[rc] * scale;

        // forget gate pre-activation: sig . Wf + b_f
        float fa[8];
        #pragma unroll
        for (int u = 0; u < 8; ++u) fa[u] = sB[8 + u];
        #pragma unroll
        for (int j = 0; j < 21; ++j) {
            float s = sg[j];
            #pragma unroll
            for (int u = 0; u < 8; ++u) fa[u] = fmaf(s, sWf[j * 8 + u], fa[u]);
        }
        // input projection + per-gate bias
        float g[24];
        #pragma unroll
        for (int u = 0; u < 8; ++u) {
            g[u] = sB[u]; g[8 + u] = sB[16 + u]; g[16 + u] = sB[24 + u];
        }
        #pragma unroll
        for (int gg = 0; gg < 24; ++gg) {
            g[gg] = fmaf(c0, sWi[gg], g[gg]);
            g[gg] = fmaf(c1, sWi[24 + gg], g[gg]);
            g[gg] = fmaf(c2, sWi[48 + gg], g[gg]);
        }
        float4* wp = (float4*)ws + ((size_t)t * BB + b) * UU;
        #pragma unroll
        for (int u = 0; u < 8; ++u)
            wp[u] = make_float4(g[u], g[8 + u], g[16 + u], fsig(fa[u]));
    }
}

// ---------- Kernel B: sequential LSTM scan, 8 lanes/batch, 8 batches/wave ----------
__global__ __launch_bounds__(64) void lstm_scan_full(
    const float* __restrict__ ws, const float* __restrict__ Wr,
    float* __restrict__ out)
{
    const int lane = threadIdx.x;
    const int u = lane & 7;
    const int q = lane >> 3;
    const int b = blockIdx.x * 8 + q;
    float wa[8], wb[8], wc[8];
    #pragma unroll
    for (int k = 0; k < 8; ++k) {
        wa[k] = Wr[k * 24 + u];
        wb[k] = Wr[k * 24 + 8 + u];
        wc[k] = Wr[k * 24 + 16 + u];
    }
    const float4* gp = (const float4*)ws + (size_t)b * 8 + u;  // + t*2048
    float4 buf[4];
    #pragma unroll
    for (int p = 0; p < 4; ++p) buf[p] = gp[(size_t)p * 2048];
    float h = 0.f, c = 0.f;
    float* op = out + (size_t)b * TT * 8 + u;
    const int base = lane & 0x38;

    for (int tb = 0; tb < TT; tb += 4) {
        #pragma unroll
        for (int j = 0; j < 4; ++j) {
            const int t = tb + j;
            float4 g = buf[j];
            if (t + 4 < TT) buf[j] = gp[(size_t)(t + 4) * 2048];  // prefetch depth 4
            float hh[8];
            #pragma unroll
            for (int k = 0; k < 8; ++k) hh[k] = __shfl(h, base + k, 64);
            float gi = g.x, gc = g.y, go = g.z, ff = g.w;
            #pragma unroll
            for (int k = 0; k < 8; ++k) {
                gi = fmaf(hh[k], wa[k], gi);
                gc = fmaf(hh[k], wb[k], gc);
                go = fmaf(hh[k], wc[k], go);
            }
            float iv = fsig(gi);
            float cv = ftanh(gc);
            float ov = fsig(go);
            c = fmaf(ff, c, iv * cv);
            h = ov * ftanh(c);
            op[(size_t)t * 8] = h;
        }
    }
}

// ---------- Fallback: no-scratch single kernel (everything per-lane on the fly) ----------
__global__ __launch_bounds__(64) void lstm_scan_ultra(
    const float* __restrict__ x, const float* __restrict__ Wi,
    const float* __restrict__ Wr, const float* __restrict__ Wf,
    const float* __restrict__ bias, float* __restrict__ out)
{
    const int lane = threadIdx.x;
    const int u = lane & 7;
    const int q = lane >> 3;
    const int b = blockIdx.x * 8 + q;
    float wa[8], wb[8], wc[8];
    #pragma unroll
    for (int k = 0; k < 8; ++k) {
        wa[k] = Wr[k * 24 + u];
        wb[k] = Wr[k * 24 + 8 + u];
        wc[k] = Wr[k * 24 + 16 + u];
    }
    float wia[3], wib[3], wic[3];
    #pragma unroll
    for (int k = 0; k < 3; ++k) {
        wia[k] = Wi[k * 24 + u];
        wib[k] = Wi[k * 24 + 8 + u];
        wic[k] = Wi[k * 24 + 16 + u];
    }
    float wf[21];
    #pragma unroll
    for (int j = 0; j < 21; ++j) wf[j] = Wf[j * 8 + u];
    const float bi = bias[u], bf = bias[8 + u], bc = bias[16 + u], bo = bias[24 + u];
    const float* xb = x + (size_t)b * TT * 3;
    float l1[4] = {0.f, 0.f, 0.f, 0.f};
    float l2[16];
    #pragma unroll
    for (int i = 0; i < 16; ++i) l2[i] = 0.f;
    float xp0 = xb[0], xp1 = xb[1], xp2 = xb[2];
    float h = 0.f, c = 0.f;
    const int base = lane & 0x38;
    float* op = out + (size_t)b * TT * 8 + u;
    const float dtc = 1.0f / 4095.0f;
    for (int t = 0; t < TT; ++t) {
        float c0 = xb[t * 3 + 0], c1 = xb[t * 3 + 1], c2 = xb[t * 3 + 2];
        if (t > 0) {
            float dxv[4] = {dtc, c0 - xp0, c1 - xp1, c2 - xp2};
            #pragma unroll
            for (int r = 0; r < 4; ++r) {
                float tr = l1[r] + 0.5f * dxv[r];
                #pragma unroll
                for (int cc = 0; cc < 4; ++cc)
                    l2[r * 4 + cc] = fmaf(tr, dxv[cc], l2[r * 4 + cc]);
            }
            #pragma unroll
            for (int r = 0; r < 4; ++r) l1[r] += dxv[r];
        }
        xp0 = c0; xp1 = c1; xp2 = c2;
        const float scale = (t == 0) ? 1.0f : (4095.0f / (float)t);
        float dot = wf[0];
        #pragma unroll
        for (int r = 0; r < 4; ++r) dot = fmaf(l1[r], wf[1 + r], dot);
        #pragma unroll
        for (int rc = 0; rc < 16; ++rc) dot = fmaf(l2[rc], wf[5 + rc], dot);
        float fv = fsig(fmaf(scale, dot, bf));
        float gi = bi, gc = bc, go = bo;
        #pragma unroll
        for (int k = 0; k < 3; ++k) {
            float xv = (k == 0) ? c0 : (k == 1) ? c1 : c2;
            gi = fmaf(xv, wia[k], gi);
            gc = fmaf(xv, wib[k], gc);
            go = fmaf(xv, wic[k], go);
        }
        float hh[8];
        #pragma unroll
        for (int k = 0; k < 8; ++k) hh[k] = __shfl(h, base + k, 64);
        #pragma unroll
        for (int k = 0; k < 8; ++k) {
            gi = fmaf(hh[k], wa[k], gi);
            gc = fmaf(hh[k], wb[k], gc);
            go = fmaf(hh[k], wc[k], go);
        }
        float iv = fsig(gi);
        float cv = ftanh(gc);
        float ov = fsig(go);
        c = fmaf(fv, c, iv * cv);
        h = ov * ftanh(c);
        op[(size_t)t * 8] = h;
    }
}

extern "C" void kernel_launch(void* const* d_in, const int* in_sizes, int n_in,
                              void* d_out, int out_size, void* d_ws, size_t ws_size,
                              hipStream_t stream) {
    const float* x    = (const float*)d_in[0];  // (256,4096,3)
    const float* Wi   = (const float*)d_in[1];  // (3,24)
    const float* Wr   = (const float*)d_in[2];  // (8,24)
    const float* Wf   = (const float*)d_in[3];  // (21,8)
    const float* bias = (const float*)d_in[4];  // (32,)
    float* out = (float*)d_out;                 // (256,4096,8)

    const size_t need = (size_t)TT * BB * UU * 4 * sizeof(float);  // 128 MiB
    if (ws_size >= need) {
        sig_pre_kernel<<<dim3(BB), dim3(256), 0, stream>>>(x, Wi, Wf, bias, (float*)d_ws);
        lstm_scan_full<<<dim3(BB / 8), dim3(64), 0, stream>>>((const float*)d_ws, Wr, out);
    } else {
        lstm_scan_ultra<<<dim3(BB / 8), dim3(64), 0, stream>>>(x, Wi, Wr, Wf, bias, out);
    }
}

// Round 2
// 652.479 us; speedup vs baseline: 1.4364x; 1.4364x over previous
//
#include <hip/hip_runtime.h>
#include <hip/hip_bf16.h>

#define TT 4096
#define BB 256
#define DD 3
#define UU 8

// ---------- fast activations ----------
#if defined(__has_builtin)
#if __has_builtin(__builtin_amdgcn_exp2f) && __has_builtin(__builtin_amdgcn_rcpf)
#define FAST_EXP2(x) __builtin_amdgcn_exp2f(x)
#define FAST_RCP(x)  __builtin_amdgcn_rcpf(x)
#endif
#endif
#ifndef FAST_EXP2
#define FAST_EXP2(x) exp2f(x)
#define FAST_RCP(x)  (1.0f / (x))
#endif

__device__ __forceinline__ float fsig(float x) {
    float e = FAST_EXP2(-1.4426950408889634f * x);
    return FAST_RCP(1.0f + e);
}
__device__ __forceinline__ float ftanh(float x) {
    float e = FAST_EXP2(2.8853900817779268f * x);
    return 1.0f - 2.0f * FAST_RCP(1.0f + e);
}

// ---------- pure-VALU cross-lane via DPP ----------
// quad_perm xor1=0xB1, xor2=0x4E, xor3=0x1B; row_half_mirror(0x141)=xor7 within 8.
template <int CTRL>
__device__ __forceinline__ float dpp_f(float v) {
    int i = __builtin_bit_cast(int, v);
    i = __builtin_amdgcn_update_dpp(0, i, CTRL, 0xF, 0xF, true);
    return __builtin_bit_cast(float, i);
}

// ---------- block-wide exclusive scan over 256 threads ----------
__device__ __forceinline__ float block_excl_scan(float v, int tid, float* red) {
    float x = v;
    int lid = tid & 63;
    #pragma unroll
    for (int d = 1; d < 64; d <<= 1) {
        float y = __shfl_up(x, d, 64);
        if (lid >= d) x += y;
    }
    int wave = tid >> 6;
    __syncthreads();
    if (lid == 63) red[wave] = x;
    __syncthreads();
    float off = 0.0f;
    for (int w = 0; w < wave; ++w) off += red[w];
    return off + (x - v);
}

// ---------- Kernel A: signature + forget gate + input projection precompute ----------
// ws layout: [t][b][u] float4 = {gi_pre, gc_pre, go_pre, f_sigmoided}
__global__ __launch_bounds__(256) void sig_pre_kernel(
    const float* __restrict__ x,     // (B,T,3)
    const float* __restrict__ Wi,    // (3,24)
    const float* __restrict__ Wf,    // (21,8)
    const float* __restrict__ bias,  // (32)
    float* __restrict__ ws)
{
    __shared__ float sWf[21 * 8];
    __shared__ float sWi[3 * 24];
    __shared__ float sB[32];
    __shared__ float red[4];

    const int tid = threadIdx.x;
    const int b = blockIdx.x;
    if (tid < 168) sWf[tid] = Wf[tid];
    if (tid < 72)  sWi[tid] = Wi[tid];
    if (tid < 32)  sB[tid]  = bias[tid];
    __syncthreads();

    const float dtc = 1.0f / 4095.0f;
    const int t0 = tid * 16;
    const float* xb = x + (size_t)b * TT * DD;

    float l1[4] = {0.f, 0.f, 0.f, 0.f};
    float l2[16];
    #pragma unroll
    for (int i = 0; i < 16; ++i) l2[i] = 0.f;
    {
        int s = (tid == 0) ? 1 : t0;
        float xp0 = xb[(s - 1) * 3 + 0];
        float xp1 = xb[(s - 1) * 3 + 1];
        float xp2 = xb[(s - 1) * 3 + 2];
        for (; s < t0 + 16; ++s) {
            float c0 = xb[s * 3 + 0], c1 = xb[s * 3 + 1], c2 = xb[s * 3 + 2];
            float dxv[4] = {dtc, c0 - xp0, c1 - xp1, c2 - xp2};
            #pragma unroll
            for (int r = 0; r < 4; ++r) {
                float tr = l1[r] + 0.5f * dxv[r];
                #pragma unroll
                for (int cc = 0; cc < 4; ++cc)
                    l2[r * 4 + cc] = fmaf(tr, dxv[cc], l2[r * 4 + cc]);
            }
            #pragma unroll
            for (int r = 0; r < 4; ++r) l1[r] += dxv[r];
            xp0 = c0; xp1 = c1; xp2 = c2;
        }
    }

    float S1[4], O1[4];
    #pragma unroll
    for (int r = 0; r < 4; ++r) { S1[r] = l1[r]; }
    for (int r = 0; r < 4; ++r) O1[r] = block_excl_scan(S1[r], tid, red);
    float O2[16];
    for (int rc = 0; rc < 16; ++rc) {
        float c2v = l2[rc] + O1[rc >> 2] * S1[rc & 3];
        O2[rc] = block_excl_scan(c2v, tid, red);
    }

    #pragma unroll
    for (int r = 0; r < 4; ++r) l1[r] = O1[r];
    #pragma unroll
    for (int i = 0; i < 16; ++i) l2[i] = O2[i];

    float xp0, xp1, xp2;
    {
        int tp = (tid == 0) ? 0 : (t0 - 1);
        xp0 = xb[tp * 3 + 0]; xp1 = xb[tp * 3 + 1]; xp2 = xb[tp * 3 + 2];
    }
    for (int i2 = 0; i2 < 16; ++i2) {
        const int t = t0 + i2;
        float c0 = xb[t * 3 + 0], c1 = xb[t * 3 + 1], c2 = xb[t * 3 + 2];
        if (t > 0) {
            float dxv[4] = {dtc, c0 - xp0, c1 - xp1, c2 - xp2};
            #pragma unroll
            for (int r = 0; r < 4; ++r) {
                float tr = l1[r] + 0.5f * dxv[r];
                #pragma unroll
                for (int cc = 0; cc < 4; ++cc)
                    l2[r * 4 + cc] = fmaf(tr, dxv[cc], l2[r * 4 + cc]);
            }
            #pragma unroll
            for (int r = 0; r < 4; ++r) l1[r] += dxv[r];
        }
        xp0 = c0; xp1 = c1; xp2 = c2;
        const float scale = (t == 0) ? 1.0f : (4095.0f / (float)t);
        float sg[21];
        sg[0] = scale;
        #pragma unroll
        for (int r = 0; r < 4; ++r) sg[1 + r] = l1[r] * scale;
        #pragma unroll
        for (int rc = 0; rc < 16; ++rc) sg[5 + rc] = l2[rc] * scale;

        float fa[8];
        #pragma unroll
        for (int u = 0; u < 8; ++u) fa[u] = sB[8 + u];
        #pragma unroll
        for (int j = 0; j < 21; ++j) {
            float s = sg[j];
            #pragma unroll
            for (int u = 0; u < 8; ++u) fa[u] = fmaf(s, sWf[j * 8 + u], fa[u]);
        }
        float g[24];
        #pragma unroll
        for (int u = 0; u < 8; ++u) {
            g[u] = sB[u]; g[8 + u] = sB[16 + u]; g[16 + u] = sB[24 + u];
        }
        #pragma unroll
        for (int gg = 0; gg < 24; ++gg) {
            g[gg] = fmaf(c0, sWi[gg], g[gg]);
            g[gg] = fmaf(c1, sWi[24 + gg], g[gg]);
            g[gg] = fmaf(c2, sWi[48 + gg], g[gg]);
        }
        float4* wp = (float4*)ws + ((size_t)t * BB + b) * UU;
        #pragma unroll
        for (int u = 0; u < 8; ++u)
            wp[u] = make_float4(g[u], g[8 + u], g[16 + u], fsig(fa[u]));
    }
}

// ---------- Kernel B: sequential LSTM scan, DPP butterfly broadcast ----------
// lane = q*8+u : batch b = blockIdx*8+q, unit u. hh[m] = h of unit u^m (same q).
__global__ __launch_bounds__(64) void lstm_scan_full(
    const float* __restrict__ ws, const float* __restrict__ Wr,
    float* __restrict__ out)
{
    const int lane = threadIdx.x;
    const int u = lane & 7;
    const int b = blockIdx.x * 8 + (lane >> 3);
    // weight for source unit j = u^m, destination unit u
    float wa[8], wb[8], wc[8];
    #pragma unroll
    for (int m = 0; m < 8; ++m) {
        int j = u ^ m;
        wa[m] = Wr[j * 24 + u];
        wb[m] = Wr[j * 24 + 8 + u];
        wc[m] = Wr[j * 24 + 16 + u];
    }
    const float4* gp = (const float4*)ws + (size_t)b * 8 + u;  // + t*2048
    float4 buf[8];                                             // prefetch ring depth 8
    #pragma unroll
    for (int p = 0; p < 8; ++p) buf[p] = gp[(size_t)p * 2048];
    float h = 0.f, c = 0.f;
    float* op = out + (size_t)b * TT * 8 + u;

    auto step = [&](int t, float4 g) {
        // DPP xor-butterfly broadcast of h across the 8-lane group
        float h1 = dpp_f<0xB1>(h);    // xor 1
        float h2 = dpp_f<0x4E>(h);    // xor 2
        float h3 = dpp_f<0x1B>(h);    // xor 3
        float h7 = dpp_f<0x141>(h);   // xor 7 (row_half_mirror)
        float h6 = dpp_f<0xB1>(h7);   // xor 6
        float h5 = dpp_f<0x4E>(h7);   // xor 5
        float h4 = dpp_f<0x1B>(h7);   // xor 4
        // two chains of 4 per gate, then combine (shorter dependent chain)
        float gi = fmaf(h, wa[0], g.x), giB = h4 * wa[4];
        float gc = fmaf(h, wb[0], g.y), gcB = h4 * wb[4];
        float go = fmaf(h, wc[0], g.z), goB = h4 * wc[4];
        gi = fmaf(h1, wa[1], gi);  giB = fmaf(h5, wa[5], giB);
        gc = fmaf(h1, wb[1], gc);  gcB = fmaf(h5, wb[5], gcB);
        go = fmaf(h1, wc[1], go);  goB = fmaf(h5, wc[5], goB);
        gi = fmaf(h2, wa[2], gi);  giB = fmaf(h6, wa[6], giB);
        gc = fmaf(h2, wb[2], gc);  gcB = fmaf(h6, wb[6], gcB);
        go = fmaf(h2, wc[2], go);  goB = fmaf(h6, wc[6], goB);
        gi = fmaf(h3, wa[3], gi);  giB = fmaf(h7, wa[7], giB);
        gc = fmaf(h3, wb[3], gc);  gcB = fmaf(h7, wb[7], gcB);
        go = fmaf(h3, wc[3], go);  goB = fmaf(h7, wc[7], goB);
        gi += giB; gc += gcB; go += goB;
        float iv = fsig(gi);
        float cv = ftanh(gc);
        float ov = fsig(go);
        c = fmaf(g.w, c, iv * cv);
        h = ov * ftanh(c);
        op[(size_t)t * 8] = h;
    };

    for (int tb = 0; tb + 8 < TT; tb += 8) {
        #pragma unroll
        for (int j = 0; j < 8; ++j) {
            const int t = tb + j;
            float4 g = buf[j];
            buf[j] = gp[(size_t)(t + 8) * 2048];   // prefetch depth 8
            step(t, g);
        }
    }
    #pragma unroll
    for (int j = 0; j < 8; ++j) step(TT - 8 + j, buf[j]);
}

// ---------- Fallback: no-scratch single kernel ----------
__global__ __launch_bounds__(64) void lstm_scan_ultra(
    const float* __restrict__ x, const float* __restrict__ Wi,
    const float* __restrict__ Wr, const float* __restrict__ Wf,
    const float* __restrict__ bias, float* __restrict__ out)
{
    const int lane = threadIdx.x;
    const int u = lane & 7;
    const int q = lane >> 3;
    const int b = blockIdx.x * 8 + q;
    float wa[8], wb[8], wc[8];
    #pragma unroll
    for (int m = 0; m < 8; ++m) {
        int j = u ^ m;
        wa[m] = Wr[j * 24 + u];
        wb[m] = Wr[j * 24 + 8 + u];
        wc[m] = Wr[j * 24 + 16 + u];
    }
    float wia[3], wib[3], wic[3];
    #pragma unroll
    for (int k = 0; k < 3; ++k) {
        wia[k] = Wi[k * 24 + u];
        wib[k] = Wi[k * 24 + 8 + u];
        wic[k] = Wi[k * 24 + 16 + u];
    }
    float wf[21];
    #pragma unroll
    for (int j = 0; j < 21; ++j) wf[j] = Wf[j * 8 + u];
    const float bi = bias[u], bf = bias[8 + u], bc = bias[16 + u], bo = bias[24 + u];
    const float* xb = x + (size_t)b * TT * 3;
    float l1[4] = {0.f, 0.f, 0.f, 0.f};
    float l2[16];
    #pragma unroll
    for (int i = 0; i < 16; ++i) l2[i] = 0.f;
    float xp0 = xb[0], xp1 = xb[1], xp2 = xb[2];
    float h = 0.f, c = 0.f;
    float* op = out + (size_t)b * TT * 8 + u;
    const float dtc = 1.0f / 4095.0f;
    for (int t = 0; t < TT; ++t) {
        float c0 = xb[t * 3 + 0], c1 = xb[t * 3 + 1], c2 = xb[t * 3 + 2];
        if (t > 0) {
            float dxv[4] = {dtc, c0 - xp0, c1 - xp1, c2 - xp2};
            #pragma unroll
            for (int r = 0; r < 4; ++r) {
                float tr = l1[r] + 0.5f * dxv[r];
                #pragma unroll
                for (int cc = 0; cc < 4; ++cc)
                    l2[r * 4 + cc] = fmaf(tr, dxv[cc], l2[r * 4 + cc]);
            }
            #pragma unroll
            for (int r = 0; r < 4; ++r) l1[r] += dxv[r];
        }
        xp0 = c0; xp1 = c1; xp2 = c2;
        const float scale = (t == 0) ? 1.0f : (4095.0f / (float)t);
        float dot = wf[0];
        #pragma unroll
        for (int r = 0; r < 4; ++r) dot = fmaf(l1[r], wf[1 + r], dot);
        #pragma unroll
        for (int rc = 0; rc < 16; ++rc) dot = fmaf(l2[rc], wf[5 + rc], dot);
        float fv = fsig(fmaf(scale, dot, bf));
        float gi = bi, gc = bc, go = bo;
        gi = fmaf(c0, wia[0], gi); gi = fmaf(c1, wia[1], gi); gi = fmaf(c2, wia[2], gi);
        gc = fmaf(c0, wib[0], gc); gc = fmaf(c1, wib[1], gc); gc = fmaf(c2, wib[2], gc);
        go = fmaf(c0, wic[0], go); go = fmaf(c1, wic[1], go); go = fmaf(c2, wic[2], go);
        float h1 = dpp_f<0xB1>(h);
        float h2 = dpp_f<0x4E>(h);
        float h3 = dpp_f<0x1B>(h);
        float h7 = dpp_f<0x141>(h);
        float h6 = dpp_f<0xB1>(h7);
        float h5 = dpp_f<0x4E>(h7);
        float h4 = dpp_f<0x1B>(h7);
        gi = fmaf(h, wa[0], gi); gi = fmaf(h1, wa[1], gi); gi = fmaf(h2, wa[2], gi); gi = fmaf(h3, wa[3], gi);
        gi = fmaf(h4, wa[4], gi); gi = fmaf(h5, wa[5], gi); gi = fmaf(h6, wa[6], gi); gi = fmaf(h7, wa[7], gi);
        gc = fmaf(h, wb[0], gc); gc = fmaf(h1, wb[1], gc); gc = fmaf(h2, wb[2], gc); gc = fmaf(h3, wb[3], gc);
        gc = fmaf(h4, wb[4], gc); gc = fmaf(h5, wb[5], gc); gc = fmaf(h6, wb[6], gc); gc = fmaf(h7, wb[7], gc);
        go = fmaf(h, wc[0], go); go = fmaf(h1, wc[1], go); go = fmaf(h2, wc[2], go); go = fmaf(h3, wc[3], go);
        go = fmaf(h4, wc[4], go); go = fmaf(h5, wc[5], go); go = fmaf(h6, wc[6], go); go = fmaf(h7, wc[7], go);
        float iv = fsig(gi);
        float cv = ftanh(gc);
        float ov = fsig(go);
        c = fmaf(fv, c, iv * cv);
        h = ov * ftanh(c);
        op[(size_t)t * 8] = h;
    }
}

extern "C" void kernel_launch(void* const* d_in, const int* in_sizes, int n_in,
                              void* d_out, int out_size, void* d_ws, size_t ws_size,
                              hipStream_t stream) {
    const float* x    = (const float*)d_in[0];  // (256,4096,3)
    const float* Wi   = (const float*)d_in[1];  // (3,24)
    const float* Wr   = (const float*)d_in[2];  // (8,24)
    const float* Wf   = (const float*)d_in[3];  // (21,8)
    const float* bias = (const float*)d_in[4];  // (32,)
    float* out = (float*)d_out;                 // (256,4096,8)

    const size_t need = (size_t)TT * BB * UU * 4 * sizeof(float);  // 128 MiB
    if (ws_size >= need) {
        sig_pre_kernel<<<dim3(BB), dim3(256), 0, stream>>>(x, Wi, Wf, bias, (float*)d_ws);
        lstm_scan_full<<<dim3(BB / 8), dim3(64), 0, stream>>>((const float*)d_ws, Wr, out);
    } else {
        lstm_scan_ultra<<<dim3(BB / 8), dim3(64), 0, stream>>>(x, Wi, Wr, Wf, bias, out);
    }
}